// Round 17
// baseline (321.110 us; speedup 1.0000x reference)
//
#include <hip/hip_runtime.h>
#include <cstddef>
#include <cstdint>

// Problem constants (reference: B=2, T=2048, D=1024, H=16, DH=64, NU=1024)
namespace {
constexpr int B_ = 2, T_ = 2048, D_ = 1024, H_ = 16, DH_ = 64, NU_ = 1024;
constexpr float SCALE = 0.03125f;           // NU^-0.5 = 1/32
constexpr size_t OUT_ELEMS = (size_t)B_ * T_ * NU_;   // 4,194,304
}

using f4  = __attribute__((ext_vector_type(4))) float;
using s8v = __attribute__((ext_vector_type(8))) short;   // 8 bf16 (4 VGPRs)
using s4v = __attribute__((ext_vector_type(4))) short;

#define MFMA16(a, b, c) __builtin_amdgcn_mfma_f32_16x16x32_bf16((a), (b), (c), 0, 0, 0)

__device__ __forceinline__ float4 ld4(const float* p) { return *reinterpret_cast<const float4*>(p); }
__device__ __forceinline__ void st4(float* p, const float4 v) { *reinterpret_cast<float4*>(p) = v; }
__device__ __forceinline__ short f2bf(float f) {      // fp32 -> bf16 RNE
    union { float f; uint32_t u; } v{f};
    uint32_t r = (v.u + 0x7fffu + ((v.u >> 16) & 1u)) >> 16;
    return (short)r;
}

#if __has_builtin(__builtin_amdgcn_global_load_lds)
#define HAVE_GLOAD_LDS 1
__device__ __forceinline__ void load_lds16(const void* g, void* l) {
    __builtin_amdgcn_global_load_lds(
        (const __attribute__((address_space(1))) void*)g,
        (__attribute__((address_space(3))) void*)l, 16, 0, 0);
}
#else
#define HAVE_GLOAD_LDS 0
#endif

// ---------------------------------------------------------------------------
// Convert queries/keys fp32 -> bf16 row-major. grid (2048, 2).
// ---------------------------------------------------------------------------
__global__ __launch_bounds__(256) void cvt_x_kernel(
    const float* __restrict__ q, const float* __restrict__ k,
    short* __restrict__ qx, short* __restrict__ kx)
{
    const float* src = blockIdx.y ? k : q;
    short* dst       = blockIdx.y ? kx : qx;
    size_t i = ((size_t)blockIdx.x * 256 + threadIdx.x) * 8;
    float4 a = ld4(src + i), b = ld4(src + i + 4);
    s8v o = { f2bf(a.x), f2bf(a.y), f2bf(a.z), f2bf(a.w),
              f2bf(b.x), f2bf(b.y), f2bf(b.z), f2bf(b.w) };
    *reinterpret_cast<s8v*>(dst + i) = o;
}

// ---------------------------------------------------------------------------
// Convert + transpose W fp32 [K][N] -> bf16 Wt [N][K]. grid (16,16,3).
// ---------------------------------------------------------------------------
__global__ __launch_bounds__(256) void cvt_w_kernel(
    const float* __restrict__ Wq, const float* __restrict__ Wk,
    const float* __restrict__ Wv, short* __restrict__ wt3)
{
    const int z = blockIdx.z;
    const float* W = (z == 0) ? Wq : (z == 1) ? Wk : Wv;
    short* dst = wt3 + (size_t)z * D_ * NU_;
    const int n0 = blockIdx.x * 64, k0 = blockIdx.y * 64;
    __shared__ float tl[64][68];
    const int rr = threadIdx.x >> 2, cc = (threadIdx.x & 3) * 16;
    const float* s = W + (size_t)(k0 + rr) * NU_ + n0 + cc;
    st4(&tl[rr][cc + 0],  ld4(s + 0));
    st4(&tl[rr][cc + 4],  ld4(s + 4));
    st4(&tl[rr][cc + 8],  ld4(s + 8));
    st4(&tl[rr][cc + 12], ld4(s + 12));
    __syncthreads();
    short* d = dst + (size_t)(n0 + rr) * D_ + k0 + cc;
#pragma unroll
    for (int c = 0; c < 4; ++c) {
        s4v o = { f2bf(tl[cc + c * 4 + 0][rr]), f2bf(tl[cc + c * 4 + 1][rr]),
                  f2bf(tl[cc + c * 4 + 2][rr]), f2bf(tl[cc + c * 4 + 3][rr]) };
        *reinterpret_cast<s4v*>(d + c * 4) = o;
    }
}

// ---------------------------------------------------------------------------
// QKV projection + wts zero-fill in ONE dispatch. blocks [0,768): bf16 MFMA
// proj (128x128 tile, BK=64, global_load_lds, XCD remap 768 = 8x96);
// blocks [768,4864): zero-fill the fully-above-diagonal wts chunks (the
// ch > chmax part of each (bh,qt2,jb) group — exactly what attn_wts's else
// branch covered). Fill needs no inputs, and proj is compute-bound with
// idle store BW -> the 235MB fill stream overlaps proj's MFMA instead of
// extending the store-bound wts kernel. grid 4864, 256 threads.
// ---------------------------------------------------------------------------
__global__ __launch_bounds__(256) void proj_mfma(
    const short* __restrict__ qx, const short* __restrict__ kx,
    const short* __restrict__ wt3,
    const float* __restrict__ bq, const float* __restrict__ bk,
    const float* __restrict__ bv,
    short* __restrict__ qb, short* __restrict__ kb, short* __restrict__ vt,
    float* __restrict__ wts)
{
    const int bid = blockIdx.x;
    const int t = threadIdx.x, w = t >> 6, l = t & 63;

    if (bid >= 768) {
        // ---- wts zero-fill blocks ----
        const int f = bid - 768;               // 0..4095
        const int xcd = f & 7, v = f >> 3;     // v: 0..511
        const int bh  = xcd * 4 + (v >> 7);
        const int rem = v & 127;
        const int qt2 = 15 - (rem >> 3);
        const int jb  = rem & 7;
        const int r0 = qt2 * 128;
        const int chmax = 2 * qt2 + 1;         // last chunk with score work
        const float4 z4 = make_float4(0.f, 0.f, 0.f, 0.f);
#pragma unroll
        for (int cx = 0; cx < 4; ++cx) {
            const int ch = jb * 4 + cx;
            if (ch > chmax) {
                const int jc = ch * 64;
#pragma unroll
                for (int half = 0; half < 2; ++half) {
                    float* dst = &wts[((size_t)bh * T_ + r0 + half * 64 + (t >> 2)) * T_
                                      + jc + (t & 3) * 16];
                    st4(dst + 0, z4); st4(dst + 4, z4);
                    st4(dst + 8, z4); st4(dst + 12, z4);
                }
            }
        }
        return;
    }

    // ---- proj blocks (XCD-chunked remap over 768) ----
    const int lin = bid;
    const int virt = (lin & 7) * 96 + (lin >> 3);
    const int z = virt >> 8, rem = virt & 255;
    const int m0 = (rem >> 3) * 128, n0 = (rem & 7) * 128;

    const short* __restrict__ X  = (z == 0) ? qx : kx;
    const short* __restrict__ Wt = wt3 + (size_t)z * D_ * NU_;
    const float* __restrict__ bias = (z == 0) ? bq : (z == 1) ? bk : bv;

    const int lr = l & 15, lg = l >> 4;
    const int wr = w >> 1, wc = w & 1;

    __shared__ short Asl[128 * 64];   // [row][k] linear, 16KB
    __shared__ short Bsl[128 * 64];   // [n][k] linear, 16KB

    f4 acc[4][4];
#pragma unroll
    for (int m = 0; m < 4; ++m)
#pragma unroll
        for (int n = 0; n < 4; ++n) acc[m][n] = (f4){0.f, 0.f, 0.f, 0.f};

    for (int k0 = 0; k0 < D_; k0 += 64) {
#if HAVE_GLOAD_LDS
#pragma unroll
        for (int j = 0; j < 4; ++j) {
            const int c0 = (w * 4 + j) * 64;
            const int c  = c0 + l;
            const int row = c >> 3, qo = (c & 7) * 8;
            load_lds16(X  + (size_t)(m0 + row) * D_ + k0 + qo, (char*)Asl + (size_t)c0 * 16);
            load_lds16(Wt + (size_t)(n0 + row) * D_ + k0 + qo, (char*)Bsl + (size_t)c0 * 16);
        }
        __syncthreads();
#else
        {
            const int sr = t >> 1, sc = (t & 1) * 32;
            s8v a0 = *reinterpret_cast<const s8v*>(X  + (size_t)(m0 + sr) * D_ + k0 + sc);
            s8v a1 = *reinterpret_cast<const s8v*>(X  + (size_t)(m0 + sr) * D_ + k0 + sc + 8);
            s8v a2 = *reinterpret_cast<const s8v*>(X  + (size_t)(m0 + sr) * D_ + k0 + sc + 16);
            s8v a3 = *reinterpret_cast<const s8v*>(X  + (size_t)(m0 + sr) * D_ + k0 + sc + 24);
            s8v b0 = *reinterpret_cast<const s8v*>(Wt + (size_t)(n0 + sr) * D_ + k0 + sc);
            s8v b1 = *reinterpret_cast<const s8v*>(Wt + (size_t)(n0 + sr) * D_ + k0 + sc + 8);
            s8v b2 = *reinterpret_cast<const s8v*>(Wt + (size_t)(n0 + sr) * D_ + k0 + sc + 16);
            s8v b3 = *reinterpret_cast<const s8v*>(Wt + (size_t)(n0 + sr) * D_ + k0 + sc + 24);
            __syncthreads();
            *reinterpret_cast<s8v*>(&Asl[sr * 64 + sc])      = a0;
            *reinterpret_cast<s8v*>(&Asl[sr * 64 + sc + 8])  = a1;
            *reinterpret_cast<s8v*>(&Asl[sr * 64 + sc + 16]) = a2;
            *reinterpret_cast<s8v*>(&Asl[sr * 64 + sc + 24]) = a3;
            *reinterpret_cast<s8v*>(&Bsl[sr * 64 + sc])      = b0;
            *reinterpret_cast<s8v*>(&Bsl[sr * 64 + sc + 8])  = b1;
            *reinterpret_cast<s8v*>(&Bsl[sr * 64 + sc + 16]) = b2;
            *reinterpret_cast<s8v*>(&Bsl[sr * 64 + sc + 24]) = b3;
            __syncthreads();
        }
#endif

#pragma unroll
        for (int kk = 0; kk < 2; ++kk) {
            s8v af[4], bf[4];
#pragma unroll
            for (int m = 0; m < 4; ++m)
                af[m] = *reinterpret_cast<const s8v*>(
                    &Asl[(wr * 64 + m * 16 + lr) * 64 + kk * 32 + lg * 8]);
#pragma unroll
            for (int n = 0; n < 4; ++n)
                bf[n] = *reinterpret_cast<const s8v*>(
                    &Bsl[(wc * 64 + n * 16 + lr) * 64 + kk * 32 + lg * 8]);
#pragma unroll
            for (int m = 0; m < 4; ++m)
#pragma unroll
                for (int n = 0; n < 4; ++n)
                    acc[m][n] = MFMA16(af[m], bf[n], acc[m][n]);
        }
        __syncthreads();
    }

    if (z < 2) {
        short* __restrict__ Y = (z == 0) ? qb : kb;
#pragma unroll
        for (int n = 0; n < 4; ++n) {
            const int col = n0 + wc * 64 + n * 16 + lr;
            const float bval = bias[col];
#pragma unroll
            for (int m = 0; m < 4; ++m) {
                const int row0 = m0 + wr * 64 + m * 16 + lg * 4;
#pragma unroll
                for (int r = 0; r < 4; ++r)
                    Y[(size_t)(row0 + r) * NU_ + col] = f2bf(acc[m][n][r] + bval);
            }
        }
    } else {
#pragma unroll
        for (int n = 0; n < 4; ++n) {
            const int col = n0 + wc * 64 + n * 16 + lr;   // 0..1023
            const float bval = bias[col];
            const int hh = col >> 6, dd = col & 63;
#pragma unroll
            for (int m = 0; m < 4; ++m) {
                const int Mi = m0 + wr * 64 + m * 16 + lg * 4;
                const int bb = Mi >> 11, t0 = Mi & 2047;
                s4v o = { f2bf(acc[m][n][0] + bval), f2bf(acc[m][n][1] + bval),
                          f2bf(acc[m][n][2] + bval), f2bf(acc[m][n][3] + bval) };
                *reinterpret_cast<s4v*>(vt + ((size_t)(bb * 16 + hh) * 64 + dd) * T_ + t0) = o;
            }
        }
    }
}

// ---------------------------------------------------------------------------
// Attention pass A (PV + rowsums + out), 4-band 64-row blocks (R12 exact —
// best measured; setprio was null in R16). grid 1024, 256 threads, 33KB
// LDS. XCD-chunked; heavy tiles first.
// ---------------------------------------------------------------------------
__global__ __launch_bounds__(256) void attn_pv_mfma(
    const short* __restrict__ qb, const short* __restrict__ kb,
    const short* __restrict__ vt, float* __restrict__ rsws,
    float* __restrict__ out)
{
    const int lin = blockIdx.x;
    const int xcd = lin & 7, v = lin >> 3;     // v: 0..127
    const int bh  = xcd * 4 + (v >> 5);
    const int g64 = 31 - (v & 31);             // heavy 64-row tiles first
    const int b = bh >> 4, h = bh & 15;
    const int r0 = g64 * 64;
    const int t = threadIdx.x, w = t >> 6, l = t & 63;
    const int lr = l & 15, lg = l >> 4;
    const int tile16 = g64;                    // diagonal chunk (r0/64)

    __shared__ __align__(16) char smem[32 * 1024 + 1024];
    short* Pl    = (short*)smem;               // [band][wave][16][64] bf16, 32KB
    float* OA    = (float*)smem;               // 16KB alias (post-barrier)
    float* rsbuf = (float*)(smem + 32 * 1024); // [band][64]

    // Q fragments, 4 bands (B-operand: col=lane&15=q-row)
    const short* qrow0 = qb + (size_t)(b * T_ + r0 + lr) * NU_ + h * DH_ + lg * 8;
    s8v qf[4][2];
#pragma unroll
    for (int d = 0; d < 4; ++d) {
        qf[d][0] = *reinterpret_cast<const s8v*>(qrow0 + (size_t)d * 16 * NU_);
        qf[d][1] = *reinterpret_cast<const s8v*>(qrow0 + (size_t)d * 16 * NU_ + 32);
    }

    f4 acc[4][4];                              // [band][nt]
#pragma unroll
    for (int d = 0; d < 4; ++d)
#pragma unroll
        for (int nt = 0; nt < 4; ++nt) acc[d][nt] = (f4){0.f, 0.f, 0.f, 0.f};
    float rsum[4] = {0.f, 0.f, 0.f, 0.f};
    const f4 zf = (f4){0.f, 0.f, 0.f, 0.f};
    const int sw = (lr & 7) << 3;              // P swizzle keyed on q-row
    const short* kbase0 = kb + (size_t)(b * T_) * NU_ + h * DH_ + lg * 8;
    short* PlW[4];
#pragma unroll
    for (int d = 0; d < 4; ++d) PlW[d] = &Pl[d * 4096 + w * 1024 + lr * 64];

    for (int ch = w; ch <= tile16; ch += 4) {
        const int jc = ch * 64;
        const bool diag = (ch == tile16);
        const short* kbase = kbase0 + (size_t)jc * NU_;

        // ---- swapped QK^T + exp + P-write; all 4 bands share kf ----
#pragma unroll
        for (int nt = 0; nt < 4; ++nt) {
            const short* kr = kbase + (size_t)(nt * 16 + lr) * NU_;
            s8v kf0 = *reinterpret_cast<const s8v*>(kr);
            s8v kf1 = *reinterpret_cast<const s8v*>(kr + 32);
            const int jl = nt * 16 + lg * 4;   // lane's j base this nt
#pragma unroll
            for (int d = 0; d < 4; ++d) {
                f4 a = MFMA16(kf0, qf[d][0], zf);
                f4 s = MFMA16(kf1, qf[d][1], a);
                float e[4];
#pragma unroll
                for (int r = 0; r < 4; ++r) {
                    float vv = __expf(s[r] * SCALE);
                    if (diag && (jl + r > d * 16 + lr)) vv = 0.f;
                    e[r] = vv;
                }
                rsum[d] += (e[0] + e[1]) + (e[2] + e[3]);
                s4v pv = { f2bf(e[0]), f2bf(e[1]), f2bf(e[2]), f2bf(e[3]) };
                *reinterpret_cast<s4v*>(PlW[d] + (jl ^ sw)) = pv;
            }
        }

        // ---- PV: all 4 bands share vf ----
        s8v pf[4][2];
#pragma unroll
        for (int d = 0; d < 4; ++d) {
            pf[d][0] = *reinterpret_cast<const s8v*>(PlW[d] + ((lg * 8) ^ sw));
            pf[d][1] = *reinterpret_cast<const s8v*>(PlW[d] + ((32 + lg * 8) ^ sw));
        }
#pragma unroll
        for (int nt = 0; nt < 4; ++nt) {
            const short* vr = vt + (size_t)(bh * 64 + nt * 16 + lr) * T_ + jc + lg * 8;
            s8v vf0 = *reinterpret_cast<const s8v*>(vr);
            s8v vf1 = *reinterpret_cast<const s8v*>(vr + 32);
#pragma unroll
            for (int d = 0; d < 4; ++d) {
                acc[d][nt] = MFMA16(pf[d][0], vf0, acc[d][nt]);
                acc[d][nt] = MFMA16(pf[d][1], vf1, acc[d][nt]);
            }
        }
    }

    // in-wave rowsum combine (lanes lr,lr+16,... hold disjoint j sets)
#pragma unroll
    for (int d = 0; d < 4; ++d) {
        rsum[d] += __shfl_xor(rsum[d], 16);
        rsum[d] += __shfl_xor(rsum[d], 32);
    }

    __syncthreads();                            // all Pl reads done (OA alias)
    if (lg == 0) {
#pragma unroll
        for (int d = 0; d < 4; ++d) rsbuf[d * 64 + w * 16 + lr] = rsum[d];
    }

    // ---- 4-pass band reduce + store over aliased OA ----
#pragma unroll
    for (int d = 0; d < 4; ++d) {
#pragma unroll
        for (int nt = 0; nt < 4; ++nt)
            st4(&OA[(size_t)(w * 64 + l) * 16 + nt * 4], *(const float4*)&acc[d][nt]);
        __syncthreads();                        // OA ready (rsbuf also visible)
        float osum[4] = {0.f, 0.f, 0.f, 0.f};
#pragma unroll
        for (int wv = 0; wv < 4; ++wv) {
            float4 p = *(const float4*)&OA[(size_t)(wv * 64 + l) * 16 + w * 4];
#pragma unroll
            for (int r = 0; r < 4; ++r) osum[r] += (&p.x)[r];
        }
#pragma unroll
        for (int r = 0; r < 4; ++r) {
            const int ro = lg * 4 + r;         // local row in band 0..15
            const float rt = rsbuf[d * 64 + ro] + rsbuf[d * 64 + 16 + ro]
                           + rsbuf[d * 64 + 32 + ro] + rsbuf[d * 64 + 48 + ro];
            out[(size_t)(b * T_ + r0 + d * 16 + ro) * NU_ + h * DH_ + w * 16 + lr] =
                osum[r] / rt;
        }
        if (w == 0 && t < 16)
            rsws[(size_t)bh * T_ + r0 + d * 16 + t] =
                rsbuf[d * 64 + t] + rsbuf[d * 64 + 16 + t]
                + rsbuf[d * 64 + 32 + t] + rsbuf[d * 64 + 48 + t];
        __syncthreads();                        // OA reads done before next band
    }
}

// ---------------------------------------------------------------------------
// Attention pass B (weights, SCORE ONLY — fill handled in proj dispatch),
// 2-band: block = 128 q-rows x 256 j-cols; two 16-row bands 64 apart share
// every K fragment. Cached st4 stores. grid 4096, 256 threads.
// ---------------------------------------------------------------------------
__global__ __launch_bounds__(256) void attn_wts_mfma(
    const short* __restrict__ qb, const short* __restrict__ kb,
    const float* __restrict__ rsws, float* __restrict__ wts)
{
    const int lin = blockIdx.x;
    const int xcd = lin & 7, v = lin >> 3;     // 0..511
    const int bh  = xcd * 4 + (v >> 7);
    const int rem = v & 127;
    const int qt2 = 15 - (rem >> 3);           // heavy 128-row tiles first
    const int jb  = rem & 7;
    const int chmax = 2 * qt2 + 1;             // last chunk with score work
    if (jb * 4 > chmax) return;                // entirely fill -> done in proj
    const int b = bh >> 4, h = bh & 15;
    const int r0 = qt2 * 128;
    const int t = threadIdx.x, w = t >> 6, l = t & 63;
    const int lr = l & 15, lg = l >> 4;

    const int iA = r0 + w * 16 + lr;            // band-A q-row
    const int iB = iA + 64;                     // band-B q-row

    const short* qrowA = qb + (size_t)(b * T_ + iA) * NU_ + h * DH_ + lg * 8;
    const s8v qA0 = *reinterpret_cast<const s8v*>(qrowA);
    const s8v qA1 = *reinterpret_cast<const s8v*>(qrowA + 32);
    const s8v qB0 = *reinterpret_cast<const s8v*>(qrowA + 64 * NU_);
    const s8v qB1 = *reinterpret_cast<const s8v*>(qrowA + 64 * NU_ + 32);
    const f4 zf = (f4){0.f, 0.f, 0.f, 0.f};

    const float invA = 1.f / rsws[(size_t)bh * T_ + iA];
    const float invB = 1.f / rsws[(size_t)bh * T_ + iB];
    float* const wrowA = &wts[((size_t)bh * T_ + iA) * T_];
    float* const wrowB = &wts[((size_t)bh * T_ + iB) * T_];
    const short* kbase0 = kb + (size_t)(b * T_) * NU_ + h * DH_ + lg * 8;

#pragma unroll
    for (int cx = 0; cx < 4; ++cx) {
        const int ch = jb * 4 + cx;
        if (ch > chmax) continue;               // filled by proj dispatch
        const int jc = ch * 64;
        const short* kbase = kbase0 + (size_t)jc * NU_;
        f4 sA[4], sB[4];
#pragma unroll
        for (int nt = 0; nt < 4; ++nt) {
            const short* kr = kbase + (size_t)(nt * 16 + lr) * NU_;
            s8v kf0 = *reinterpret_cast<const s8v*>(kr);
            s8v kf1 = *reinterpret_cast<const s8v*>(kr + 32);
            f4 aA = MFMA16(kf0, qA0, zf);
            sA[nt] = MFMA16(kf1, qA1, aA);
            f4 aB = MFMA16(kf0, qB0, zf);
            sB[nt] = MFMA16(kf1, qB1, aB);
        }
#pragma unroll
        for (int nt = 0; nt < 4; ++nt) {
            float4 oA, oB;
            float* eA = &oA.x;
            float* eB = &oB.x;
#pragma unroll
            for (int r = 0; r < 4; ++r) {
                const int j = jc + nt * 16 + lg * 4 + r;
                eA[r] = (j <= iA) ? __expf(sA[nt][r] * SCALE) * invA : 0.f;
                eB[r] = (j <= iB) ? __expf(sB[nt][r] * SCALE) * invB : 0.f;
            }
            st4(wrowA + jc + nt * 16 + lg * 4, oA);
            st4(wrowB + jc + nt * 16 + lg * 4, oB);
        }
    }
}

// ---------------------------------------------------------------------------
extern "C" void kernel_launch(void* const* d_in, const int* in_sizes, int n_in,
                              void* d_out, int out_size, void* d_ws, size_t ws_size,
                              hipStream_t stream)
{
    const float* queries = (const float*)d_in[0];
    const float* keys    = (const float*)d_in[1];
    const float* Wq = (const float*)d_in[2];
    const float* bq = (const float*)d_in[3];
    const float* Wk = (const float*)d_in[4];
    const float* bk = (const float*)d_in[5];
    const float* Wv = (const float*)d_in[6];
    const float* bv = (const float*)d_in[7];

    float* out = (float*)d_out;                 // [B,T,NU]
    float* wts = out + OUT_ELEMS;               // [B,H,T,T]

    // workspace (bf16 shorts unless noted), total ~44.3 MB:
    short* qx = (short*)d_ws;                               // queries bf16 [4096][1024]
    short* kx = qx + (size_t)B_ * T_ * D_;                  // keys bf16
    short* wt = kx + (size_t)B_ * T_ * D_;                  // Wt bf16 [3][N][K]
    short* qb = wt + (size_t)3 * D_ * NU_;                  // q proj bf16 [4096][1024]
    short* kb = qb + (size_t)B_ * T_ * NU_;                 // k proj bf16
    short* vt = kb + (size_t)B_ * T_ * NU_;                 // v proj bf16, [bh][d][t]
    float* rsws = (float*)(vt + (size_t)B_ * T_ * NU_);     // rowsums [bh][t]

    cvt_x_kernel<<<dim3(2048, 2), 256, 0, stream>>>(queries, keys, qx, kx);
    cvt_w_kernel<<<dim3(16, 16, 3), 256, 0, stream>>>(Wq, Wk, Wv, wt);
    proj_mfma<<<dim3(4864), 256, 0, stream>>>(
        qx, kx, wt, bq, bk, bv, qb, kb, vt, wts);
    attn_pv_mfma<<<dim3(1024), 256, 0, stream>>>(qb, kb, vt, rsws, out);
    attn_wts_mfma<<<dim3(4096), 256, 0, stream>>>(qb, kb, rsws, wts);
}

// Round 18
// 281.740 us; speedup vs baseline: 1.1397x; 1.1397x over previous
//
#include <hip/hip_runtime.h>
#include <cstddef>
#include <cstdint>

// Problem constants (reference: B=2, T=2048, D=1024, H=16, DH=64, NU=1024)
namespace {
constexpr int B_ = 2, T_ = 2048, D_ = 1024, H_ = 16, DH_ = 64, NU_ = 1024;
constexpr float SCALE = 0.03125f;           // NU^-0.5 = 1/32
constexpr size_t OUT_ELEMS = (size_t)B_ * T_ * NU_;   // 4,194,304
}

using f4  = __attribute__((ext_vector_type(4))) float;
using s8v = __attribute__((ext_vector_type(8))) short;   // 8 bf16 (4 VGPRs)
using s4v = __attribute__((ext_vector_type(4))) short;

#define MFMA16(a, b, c) __builtin_amdgcn_mfma_f32_16x16x32_bf16((a), (b), (c), 0, 0, 0)

__device__ __forceinline__ float4 ld4(const float* p) { return *reinterpret_cast<const float4*>(p); }
__device__ __forceinline__ void st4(float* p, const float4 v) { *reinterpret_cast<float4*>(p) = v; }
__device__ __forceinline__ short f2bf(float f) {      // fp32 -> bf16 RNE
    union { float f; uint32_t u; } v{f};
    uint32_t r = (v.u + 0x7fffu + ((v.u >> 16) & 1u)) >> 16;
    return (short)r;
}

#if __has_builtin(__builtin_amdgcn_global_load_lds)
#define HAVE_GLOAD_LDS 1
__device__ __forceinline__ void load_lds16(const void* g, void* l) {
    __builtin_amdgcn_global_load_lds(
        (const __attribute__((address_space(1))) void*)g,
        (__attribute__((address_space(3))) void*)l, 16, 0, 0);
}
#else
#define HAVE_GLOAD_LDS 0
#endif

// ---------------------------------------------------------------------------
// Convert queries/keys fp32 -> bf16 row-major. grid (2048, 2).
// ---------------------------------------------------------------------------
__global__ __launch_bounds__(256) void cvt_x_kernel(
    const float* __restrict__ q, const float* __restrict__ k,
    short* __restrict__ qx, short* __restrict__ kx)
{
    const float* src = blockIdx.y ? k : q;
    short* dst       = blockIdx.y ? kx : qx;
    size_t i = ((size_t)blockIdx.x * 256 + threadIdx.x) * 8;
    float4 a = ld4(src + i), b = ld4(src + i + 4);
    s8v o = { f2bf(a.x), f2bf(a.y), f2bf(a.z), f2bf(a.w),
              f2bf(b.x), f2bf(b.y), f2bf(b.z), f2bf(b.w) };
    *reinterpret_cast<s8v*>(dst + i) = o;
}

// ---------------------------------------------------------------------------
// Convert + transpose W fp32 [K][N] -> bf16 Wt [N][K]. grid (16,16,3).
// ---------------------------------------------------------------------------
__global__ __launch_bounds__(256) void cvt_w_kernel(
    const float* __restrict__ Wq, const float* __restrict__ Wk,
    const float* __restrict__ Wv, short* __restrict__ wt3)
{
    const int z = blockIdx.z;
    const float* W = (z == 0) ? Wq : (z == 1) ? Wk : Wv;
    short* dst = wt3 + (size_t)z * D_ * NU_;
    const int n0 = blockIdx.x * 64, k0 = blockIdx.y * 64;
    __shared__ float tl[64][68];
    const int rr = threadIdx.x >> 2, cc = (threadIdx.x & 3) * 16;
    const float* s = W + (size_t)(k0 + rr) * NU_ + n0 + cc;
    st4(&tl[rr][cc + 0],  ld4(s + 0));
    st4(&tl[rr][cc + 4],  ld4(s + 4));
    st4(&tl[rr][cc + 8],  ld4(s + 8));
    st4(&tl[rr][cc + 12], ld4(s + 12));
    __syncthreads();
    short* d = dst + (size_t)(n0 + rr) * D_ + k0 + cc;
#pragma unroll
    for (int c = 0; c < 4; ++c) {
        s4v o = { f2bf(tl[cc + c * 4 + 0][rr]), f2bf(tl[cc + c * 4 + 1][rr]),
                  f2bf(tl[cc + c * 4 + 2][rr]), f2bf(tl[cc + c * 4 + 3][rr]) };
        *reinterpret_cast<s4v*>(d + c * 4) = o;
    }
}

// ---------------------------------------------------------------------------
// QKV projection, bf16 MFMA: 128x128 tile, BK=64, 4 waves, global_load_lds
// width-16 into linear [128][64] LDS. XCD-chunked remap (768 = 8 x 96).
// z=0->qb, z=1->kb, z=2->vt ([bh][d][t] transposed). grid(8,32,3), 256 thr.
// ---------------------------------------------------------------------------
__global__ __launch_bounds__(256) void proj_mfma(
    const short* __restrict__ qx, const short* __restrict__ kx,
    const short* __restrict__ wt3,
    const float* __restrict__ bq, const float* __restrict__ bk,
    const float* __restrict__ bv,
    short* __restrict__ qb, short* __restrict__ kb, short* __restrict__ vt)
{
    const int lin = blockIdx.z * 256 + blockIdx.y * 8 + blockIdx.x;
    const int virt = (lin & 7) * 96 + (lin >> 3);
    const int z = virt >> 8, rem = virt & 255;
    const int m0 = (rem >> 3) * 128, n0 = (rem & 7) * 128;

    const short* __restrict__ X  = (z == 0) ? qx : kx;
    const short* __restrict__ Wt = wt3 + (size_t)z * D_ * NU_;
    const float* __restrict__ bias = (z == 0) ? bq : (z == 1) ? bk : bv;

    const int t = threadIdx.x, w = t >> 6, l = t & 63;
    const int lr = l & 15, lg = l >> 4;
    const int wr = w >> 1, wc = w & 1;

    __shared__ short Asl[128 * 64];   // [row][k] linear, 16KB
    __shared__ short Bsl[128 * 64];   // [n][k] linear, 16KB

    f4 acc[4][4];
#pragma unroll
    for (int m = 0; m < 4; ++m)
#pragma unroll
        for (int n = 0; n < 4; ++n) acc[m][n] = (f4){0.f, 0.f, 0.f, 0.f};

    for (int k0 = 0; k0 < D_; k0 += 64) {
#if HAVE_GLOAD_LDS
#pragma unroll
        for (int j = 0; j < 4; ++j) {
            const int c0 = (w * 4 + j) * 64;
            const int c  = c0 + l;
            const int row = c >> 3, qo = (c & 7) * 8;
            load_lds16(X  + (size_t)(m0 + row) * D_ + k0 + qo, (char*)Asl + (size_t)c0 * 16);
            load_lds16(Wt + (size_t)(n0 + row) * D_ + k0 + qo, (char*)Bsl + (size_t)c0 * 16);
        }
        __syncthreads();
#else
        {
            const int sr = t >> 1, sc = (t & 1) * 32;
            s8v a0 = *reinterpret_cast<const s8v*>(X  + (size_t)(m0 + sr) * D_ + k0 + sc);
            s8v a1 = *reinterpret_cast<const s8v*>(X  + (size_t)(m0 + sr) * D_ + k0 + sc + 8);
            s8v a2 = *reinterpret_cast<const s8v*>(X  + (size_t)(m0 + sr) * D_ + k0 + sc + 16);
            s8v a3 = *reinterpret_cast<const s8v*>(X  + (size_t)(m0 + sr) * D_ + k0 + sc + 24);
            s8v b0 = *reinterpret_cast<const s8v*>(Wt + (size_t)(n0 + sr) * D_ + k0 + sc);
            s8v b1 = *reinterpret_cast<const s8v*>(Wt + (size_t)(n0 + sr) * D_ + k0 + sc + 8);
            s8v b2 = *reinterpret_cast<const s8v*>(Wt + (size_t)(n0 + sr) * D_ + k0 + sc + 16);
            s8v b3 = *reinterpret_cast<const s8v*>(Wt + (size_t)(n0 + sr) * D_ + k0 + sc + 24);
            __syncthreads();
            *reinterpret_cast<s8v*>(&Asl[sr * 64 + sc])      = a0;
            *reinterpret_cast<s8v*>(&Asl[sr * 64 + sc + 8])  = a1;
            *reinterpret_cast<s8v*>(&Asl[sr * 64 + sc + 16]) = a2;
            *reinterpret_cast<s8v*>(&Asl[sr * 64 + sc + 24]) = a3;
            *reinterpret_cast<s8v*>(&Bsl[sr * 64 + sc])      = b0;
            *reinterpret_cast<s8v*>(&Bsl[sr * 64 + sc + 8])  = b1;
            *reinterpret_cast<s8v*>(&Bsl[sr * 64 + sc + 16]) = b2;
            *reinterpret_cast<s8v*>(&Bsl[sr * 64 + sc + 24]) = b3;
            __syncthreads();
        }
#endif

#pragma unroll
        for (int kk = 0; kk < 2; ++kk) {
            s8v af[4], bf[4];
#pragma unroll
            for (int m = 0; m < 4; ++m)
                af[m] = *reinterpret_cast<const s8v*>(
                    &Asl[(wr * 64 + m * 16 + lr) * 64 + kk * 32 + lg * 8]);
#pragma unroll
            for (int n = 0; n < 4; ++n)
                bf[n] = *reinterpret_cast<const s8v*>(
                    &Bsl[(wc * 64 + n * 16 + lr) * 64 + kk * 32 + lg * 8]);
#pragma unroll
            for (int m = 0; m < 4; ++m)
#pragma unroll
                for (int n = 0; n < 4; ++n)
                    acc[m][n] = MFMA16(af[m], bf[n], acc[m][n]);
        }
        __syncthreads();
    }

    if (z < 2) {
        short* __restrict__ Y = (z == 0) ? qb : kb;
#pragma unroll
        for (int n = 0; n < 4; ++n) {
            const int col = n0 + wc * 64 + n * 16 + lr;
            const float bval = bias[col];
#pragma unroll
            for (int m = 0; m < 4; ++m) {
                const int row0 = m0 + wr * 64 + m * 16 + lg * 4;
#pragma unroll
                for (int r = 0; r < 4; ++r)
                    Y[(size_t)(row0 + r) * NU_ + col] = f2bf(acc[m][n][r] + bval);
            }
        }
    } else {
#pragma unroll
        for (int n = 0; n < 4; ++n) {
            const int col = n0 + wc * 64 + n * 16 + lr;   // 0..1023
            const float bval = bias[col];
            const int hh = col >> 6, dd = col & 63;
#pragma unroll
            for (int m = 0; m < 4; ++m) {
                const int Mi = m0 + wr * 64 + m * 16 + lg * 4;
                const int bb = Mi >> 11, t0 = Mi & 2047;
                s4v o = { f2bf(acc[m][n][0] + bval), f2bf(acc[m][n][1] + bval),
                          f2bf(acc[m][n][2] + bval), f2bf(acc[m][n][3] + bval) };
                *reinterpret_cast<s4v*>(vt + ((size_t)(bb * 16 + hh) * 64 + dd) * T_ + t0) = o;
            }
        }
    }
}

// ---------------------------------------------------------------------------
// Attention pass A (PV + rowsums + out), 4-band 64-row blocks: four 16-row
// bands share every K/V fragment (K/V-load issue per output row is 1/4 of
// the 16-row form; 4 independent MFMA chains per fragment). Waves split the
// chunk range (w, w+4, ...). P buffers: per-band per-wave LDS (32KB),
// barrier-free loop. Epilogue: 4-pass band loop over aliased 16KB OA.
// grid 1024, 256 threads. XCD-chunked; heavy tiles first. (R12 — best.)
// ---------------------------------------------------------------------------
__global__ __launch_bounds__(256) void attn_pv_mfma(
    const short* __restrict__ qb, const short* __restrict__ kb,
    const short* __restrict__ vt, float* __restrict__ rsws,
    float* __restrict__ out)
{
    const int lin = blockIdx.x;
    const int xcd = lin & 7, v = lin >> 3;     // v: 0..127
    const int bh  = xcd * 4 + (v >> 5);
    const int g64 = 31 - (v & 31);             // heavy 64-row tiles first
    const int b = bh >> 4, h = bh & 15;
    const int r0 = g64 * 64;
    const int t = threadIdx.x, w = t >> 6, l = t & 63;
    const int lr = l & 15, lg = l >> 4;
    const int tile16 = g64;                    // diagonal chunk (r0/64)

    __shared__ __align__(16) char smem[32 * 1024 + 1024];
    short* Pl    = (short*)smem;               // [band][wave][16][64] bf16, 32KB
    float* OA    = (float*)smem;               // 16KB alias (post-barrier)
    float* rsbuf = (float*)(smem + 32 * 1024); // [band][64]

    // Q fragments, 4 bands (B-operand: col=lane&15=q-row)
    const short* qrow0 = qb + (size_t)(b * T_ + r0 + lr) * NU_ + h * DH_ + lg * 8;
    s8v qf[4][2];
#pragma unroll
    for (int d = 0; d < 4; ++d) {
        qf[d][0] = *reinterpret_cast<const s8v*>(qrow0 + (size_t)d * 16 * NU_);
        qf[d][1] = *reinterpret_cast<const s8v*>(qrow0 + (size_t)d * 16 * NU_ + 32);
    }

    f4 acc[4][4];                              // [band][nt]
#pragma unroll
    for (int d = 0; d < 4; ++d)
#pragma unroll
        for (int nt = 0; nt < 4; ++nt) acc[d][nt] = (f4){0.f, 0.f, 0.f, 0.f};
    float rsum[4] = {0.f, 0.f, 0.f, 0.f};
    const f4 zf = (f4){0.f, 0.f, 0.f, 0.f};
    const int sw = (lr & 7) << 3;              // P swizzle keyed on q-row
    const short* kbase0 = kb + (size_t)(b * T_) * NU_ + h * DH_ + lg * 8;
    short* PlW[4];
#pragma unroll
    for (int d = 0; d < 4; ++d) PlW[d] = &Pl[d * 4096 + w * 1024 + lr * 64];

    for (int ch = w; ch <= tile16; ch += 4) {
        const int jc = ch * 64;
        const bool diag = (ch == tile16);
        const short* kbase = kbase0 + (size_t)jc * NU_;

        // ---- swapped QK^T + exp + P-write; all 4 bands share kf ----
#pragma unroll
        for (int nt = 0; nt < 4; ++nt) {
            const short* kr = kbase + (size_t)(nt * 16 + lr) * NU_;
            s8v kf0 = *reinterpret_cast<const s8v*>(kr);
            s8v kf1 = *reinterpret_cast<const s8v*>(kr + 32);
            const int jl = nt * 16 + lg * 4;   // lane's j base this nt
#pragma unroll
            for (int d = 0; d < 4; ++d) {
                f4 a = MFMA16(kf0, qf[d][0], zf);
                f4 s = MFMA16(kf1, qf[d][1], a);
                float e[4];
#pragma unroll
                for (int r = 0; r < 4; ++r) {
                    float vv = __expf(s[r] * SCALE);
                    if (diag && (jl + r > d * 16 + lr)) vv = 0.f;
                    e[r] = vv;
                }
                rsum[d] += (e[0] + e[1]) + (e[2] + e[3]);
                s4v pv = { f2bf(e[0]), f2bf(e[1]), f2bf(e[2]), f2bf(e[3]) };
                *reinterpret_cast<s4v*>(PlW[d] + (jl ^ sw)) = pv;
            }
        }

        // ---- PV: all 4 bands share vf ----
        s8v pf[4][2];
#pragma unroll
        for (int d = 0; d < 4; ++d) {
            pf[d][0] = *reinterpret_cast<const s8v*>(PlW[d] + ((lg * 8) ^ sw));
            pf[d][1] = *reinterpret_cast<const s8v*>(PlW[d] + ((32 + lg * 8) ^ sw));
        }
#pragma unroll
        for (int nt = 0; nt < 4; ++nt) {
            const short* vr = vt + (size_t)(bh * 64 + nt * 16 + lr) * T_ + jc + lg * 8;
            s8v vf0 = *reinterpret_cast<const s8v*>(vr);
            s8v vf1 = *reinterpret_cast<const s8v*>(vr + 32);
#pragma unroll
            for (int d = 0; d < 4; ++d) {
                acc[d][nt] = MFMA16(pf[d][0], vf0, acc[d][nt]);
                acc[d][nt] = MFMA16(pf[d][1], vf1, acc[d][nt]);
            }
        }
    }

    // in-wave rowsum combine (lanes lr,lr+16,... hold disjoint j sets)
#pragma unroll
    for (int d = 0; d < 4; ++d) {
        rsum[d] += __shfl_xor(rsum[d], 16);
        rsum[d] += __shfl_xor(rsum[d], 32);
    }

    __syncthreads();                            // all Pl reads done (OA alias)
    if (lg == 0) {
#pragma unroll
        for (int d = 0; d < 4; ++d) rsbuf[d * 64 + w * 16 + lr] = rsum[d];
    }

    // ---- 4-pass band reduce + store over aliased OA ----
#pragma unroll
    for (int d = 0; d < 4; ++d) {
#pragma unroll
        for (int nt = 0; nt < 4; ++nt)
            st4(&OA[(size_t)(w * 64 + l) * 16 + nt * 4], *(const float4*)&acc[d][nt]);
        __syncthreads();                        // OA ready (rsbuf also visible)
        float osum[4] = {0.f, 0.f, 0.f, 0.f};
#pragma unroll
        for (int wv = 0; wv < 4; ++wv) {
            float4 p = *(const float4*)&OA[(size_t)(wv * 64 + l) * 16 + w * 4];
#pragma unroll
            for (int r = 0; r < 4; ++r) osum[r] += (&p.x)[r];
        }
#pragma unroll
        for (int r = 0; r < 4; ++r) {
            const int ro = lg * 4 + r;         // local row in band 0..15
            const float rt = rsbuf[d * 64 + ro] + rsbuf[d * 64 + 16 + ro]
                           + rsbuf[d * 64 + 32 + ro] + rsbuf[d * 64 + 48 + ro];
            out[(size_t)(b * T_ + r0 + d * 16 + ro) * NU_ + h * DH_ + w * 16 + lr] =
                osum[r] / rt;
        }
        if (w == 0 && t < 16)
            rsws[(size_t)bh * T_ + r0 + d * 16 + t] =
                rsbuf[d * 64 + t] + rsbuf[d * 64 + 16 + t]
                + rsbuf[d * 64 + 32 + t] + rsbuf[d * 64 + 48 + t];
        __syncthreads();                        // OA reads done before next band
    }
}

// ---------------------------------------------------------------------------
// Attention pass B (weights), 2-band: block = 128 q-rows x 256 j-cols.
// Each wave handles two 16-row bands 64 rows apart sharing every K fragment.
// Score + zero-fill combined in one kernel (intra-dispatch overlap).
// Cached st4 stores. grid 4096, 256 threads. (R12 — best measured.)
// ---------------------------------------------------------------------------
__global__ __launch_bounds__(256) void attn_wts_mfma(
    const short* __restrict__ qb, const short* __restrict__ kb,
    const float* __restrict__ rsws, float* __restrict__ wts)
{
    const int lin = blockIdx.x;
    const int xcd = lin & 7, v = lin >> 3;     // 0..511
    const int bh  = xcd * 4 + (v >> 7);
    const int rem = v & 127;
    const int qt2 = 15 - (rem >> 3);           // heavy 128-row tiles first
    const int jb  = rem & 7;
    const int b = bh >> 4, h = bh & 15;
    const int r0 = qt2 * 128;
    const int chmax = 2 * qt2 + 1;             // last chunk with any score work
    const int t = threadIdx.x, w = t >> 6, l = t & 63;
    const int lr = l & 15, lg = l >> 4;

    const int iA = r0 + w * 16 + lr;            // band-A q-row
    const int iB = iA + 64;                     // band-B q-row

    const short* qrowA = qb + (size_t)(b * T_ + iA) * NU_ + h * DH_ + lg * 8;
    const s8v qA0 = *reinterpret_cast<const s8v*>(qrowA);
    const s8v qA1 = *reinterpret_cast<const s8v*>(qrowA + 32);
    const s8v qB0 = *reinterpret_cast<const s8v*>(qrowA + 64 * NU_);
    const s8v qB1 = *reinterpret_cast<const s8v*>(qrowA + 64 * NU_ + 32);
    const f4 zf = (f4){0.f, 0.f, 0.f, 0.f};

    const float invA = 1.f / rsws[(size_t)bh * T_ + iA];
    const float invB = 1.f / rsws[(size_t)bh * T_ + iB];
    float* const wrowA = &wts[((size_t)bh * T_ + iA) * T_];
    float* const wrowB = &wts[((size_t)bh * T_ + iB) * T_];
    const short* kbase0 = kb + (size_t)(b * T_) * NU_ + h * DH_ + lg * 8;

#pragma unroll
    for (int cx = 0; cx < 4; ++cx) {
        const int ch = jb * 4 + cx;
        const int jc = ch * 64;
        if (ch <= chmax) {
            const short* kbase = kbase0 + (size_t)jc * NU_;
            f4 sA[4], sB[4];
#pragma unroll
            for (int nt = 0; nt < 4; ++nt) {
                const short* kr = kbase + (size_t)(nt * 16 + lr) * NU_;
                s8v kf0 = *reinterpret_cast<const s8v*>(kr);
                s8v kf1 = *reinterpret_cast<const s8v*>(kr + 32);
                f4 aA = MFMA16(kf0, qA0, zf);
                sA[nt] = MFMA16(kf1, qA1, aA);
                f4 aB = MFMA16(kf0, qB0, zf);
                sB[nt] = MFMA16(kf1, qB1, aB);
            }
#pragma unroll
            for (int nt = 0; nt < 4; ++nt) {
                float4 oA, oB;
                float* eA = &oA.x;
                float* eB = &oB.x;
#pragma unroll
                for (int r = 0; r < 4; ++r) {
                    const int j = jc + nt * 16 + lg * 4 + r;
                    eA[r] = (j <= iA) ? __expf(sA[nt][r] * SCALE) * invA : 0.f;
                    eB[r] = (j <= iB) ? __expf(sB[nt][r] * SCALE) * invB : 0.f;
                }
                st4(wrowA + jc + nt * 16 + lg * 4, oA);
                st4(wrowB + jc + nt * 16 + lg * 4, oB);
            }
        } else {
            // chunk fully above both bands' diagonals: zero-fill 128 rows
            const float4 z4 = make_float4(0.f, 0.f, 0.f, 0.f);
#pragma unroll
            for (int half = 0; half < 2; ++half) {
                float* dst = &wts[((size_t)bh * T_ + r0 + half * 64 + (t >> 2)) * T_
                                  + jc + (t & 3) * 16];
                st4(dst + 0, z4); st4(dst + 4, z4);
                st4(dst + 8, z4); st4(dst + 12, z4);
            }
        }
    }
}

// ---------------------------------------------------------------------------
extern "C" void kernel_launch(void* const* d_in, const int* in_sizes, int n_in,
                              void* d_out, int out_size, void* d_ws, size_t ws_size,
                              hipStream_t stream)
{
    const float* queries = (const float*)d_in[0];
    const float* keys    = (const float*)d_in[1];
    const float* Wq = (const float*)d_in[2];
    const float* bq = (const float*)d_in[3];
    const float* Wk = (const float*)d_in[4];
    const float* bk = (const float*)d_in[5];
    const float* Wv = (const float*)d_in[6];
    const float* bv = (const float*)d_in[7];

    float* out = (float*)d_out;                 // [B,T,NU]
    float* wts = out + OUT_ELEMS;               // [B,H,T,T]

    // workspace (bf16 shorts unless noted), total ~44.3 MB:
    short* qx = (short*)d_ws;                               // queries bf16 [4096][1024]
    short* kx = qx + (size_t)B_ * T_ * D_;                  // keys bf16
    short* wt = kx + (size_t)B_ * T_ * D_;                  // Wt bf16 [3][N][K]
    short* qb = wt + (size_t)3 * D_ * NU_;                  // q proj bf16 [4096][1024]
    short* kb = qb + (size_t)B_ * T_ * NU_;                 // k proj bf16
    short* vt = kb + (size_t)B_ * T_ * NU_;                 // v proj bf16, [bh][d][t]
    float* rsws = (float*)(vt + (size_t)B_ * T_ * NU_);     // rowsums [bh][t]

    cvt_x_kernel<<<dim3(2048, 2), 256, 0, stream>>>(queries, keys, qx, kx);
    cvt_w_kernel<<<dim3(16, 16, 3), 256, 0, stream>>>(Wq, Wk, Wv, wt);
    proj_mfma<<<dim3(8, 32, 3), 256, 0, stream>>>(
        qx, kx, wt, bq, bk, bv, qb, kb, vt);
    attn_pv_mfma<<<dim3(1024), 256, 0, stream>>>(qb, kb, vt, rsws, out);
    attn_wts_mfma<<<dim3(4096), 256, 0, stream>>>(qb, kb, rsws, wts);
}